// Round 6
// baseline (241.722 us; speedup 1.0000x reference)
//
#include <hip/hip_runtime.h>

#define IMG_H 1080
#define IMG_W 1920
#define TILE_W 128
#define TILE_H 12
#define GXB (IMG_W / TILE_W)    // 15
#define GYB (IMG_H / TILE_H)    // 90
#define BAND_H (TILE_H + 6)     // 18 rows: y0-3 .. y0+14
#define BAND_W 136              // cols gx0-4 .. gx0+131
#define BAND_PW 137             // +1 pad: row-major, conflict-free
#define NCH (BAND_H * (BAND_W / 4))   // 612 float4 chunks
#define PROBE_REPS 8            // PROBE ROUND: repeat body to surface kernel in rocprof top-5

// Nonzero iff the 16-bit circular mask has 9 consecutive set bits.
// (Validated absmax=0 in prior rounds; unchanged.)
__device__ __forceinline__ unsigned det9(unsigned m) {
    unsigned x = m | (m << 16);
    unsigned t = x & (x >> 1);   // run 2
    t &= t >> 2;                 // run 4
    t &= t >> 4;                 // run 8
    t &= x >> 8;                 // run 9
    return t;
}

// m = (m << 1) | (val CMP thr) in exactly 2 VALU (v_cmp + v_addc m+m+carry).
#define STEP_GE(m, sc, val, thr)                                          \
    asm("v_cmp_ge_f32 %1, %2, %3\n\tv_addc_co_u32 %0, %1, %0, %0, %1"     \
        : "+v"(m), "=s"(sc) : "v"(val), "v"(thr))
#define STEP_LE(m, sc, val, thr)                                          \
    asm("v_cmp_le_f32 %1, %2, %3\n\tv_addc_co_u32 %0, %1, %0, %0, %1"     \
        : "+v"(m), "=s"(sc) : "v"(val), "v"(thr))

__global__ __launch_bounds__(256) void fast_score_kernel(const float* __restrict__ img,
                                                         float* __restrict__ out) {
    __shared__ float band[BAND_H][BAND_PW];   // 9864 B

    // Bijective XCD swizzle (m204 form; valid for any nwg).
    int bid = blockIdx.x;
    {
        const int nwg = gridDim.x;
        const int q = nwg >> 3, r = nwg & 7;
        const int xcd = bid & 7, idx = bid >> 3;
        bid = (xcd < r ? xcd * (q + 1) : r * (q + 1) + (xcd - r) * q) + idx;
    }
    const int bx = bid % GXB;
    const int t0 = bid / GXB;
    const int by = t0 % GYB;
    const int n  = t0 / GYB;

    const int tx  = threadIdx.x;               // 0..127
    const int ty  = threadIdx.y;               // 0..1
    const int tid = ty * TILE_W + tx;          // 0..255

    const int gx0 = bx * TILE_W;
    const int y0  = by * TILE_H;

    const float* base = img + (size_t)n * (IMG_H * IMG_W);

    // PROBE: repeat the full body; each rep ends in __syncthreads() (memory
    // barrier -> stores/loads not elided; WAR on band protected). Semantics of
    // each rep identical to the R5 kernel; output written each rep (idempotent).
#pragma unroll 1
    for (int rep = 0; rep < PROBE_REPS; ++rep) {

        // ---- stage 18x136 band into LDS (replicate-clamped) ----
        if (bx > 0 && bx < GXB - 1) {
            const int qa = tid;
            const int qb = tid + 256;
            const bool c_act = tid < (NCH - 512);            // tid < 100
            const int qc = c_act ? tid + 512 : tid;

            const int ra = qa / 34, ca = qa - ra * 34;
            const int rb = qb / 34, cb = qb - rb * 34;
            const int rc = qc / 34, cc = qc - rc * 34;

            const int rya = min(max(y0 - 3 + ra, 0), IMG_H - 1);
            const int ryb = min(max(y0 - 3 + rb, 0), IMG_H - 1);
            const int ryc = min(max(y0 - 3 + rc, 0), IMG_H - 1);

            const float4 va = *(const float4*)(base + (size_t)rya * IMG_W + (gx0 - 4 + ca * 4));
            const float4 vb = *(const float4*)(base + (size_t)ryb * IMG_W + (gx0 - 4 + cb * 4));
            const float4 vc = *(const float4*)(base + (size_t)ryc * IMG_W + (gx0 - 4 + cc * 4));

            *(float4*)&band[ra][ca * 4] = va;
            *(float4*)&band[rb][cb * 4] = vb;
            if (c_act) *(float4*)&band[rc][cc * 4] = vc;
        } else {
            for (int i = tid; i < BAND_H * BAND_W; i += 256) {
                const int r  = i / BAND_W;
                const int c  = i - r * BAND_W;
                const int ry = min(max(y0 - 3 + r, 0), IMG_H - 1);
                const int cg = min(max(gx0 - 4 + c, 0), IMG_W - 1);
                band[r][c] = base[(size_t)ry * IMG_W + cg];
            }
        }
        __syncthreads();

        constexpr int DY[16] = {0, 1, 2, 3, 3, 3, 2, 1, 0, -1, -2, -3, -3, -3, -2, -1};
        constexpr int DX[16] = {-3, -3, -2, -1, 0, 1, 2, 3, 3, 3, 2, 1, 0, -1, -2, -3};

        const int cx = tx + 4;
        const int w0 = ty * (TILE_H / 2);   // 0 or 6

        float* obase = out + ((size_t)n * IMG_H + y0 + w0) * IMG_W + gx0 + tx;

#pragma unroll
        for (int jj = 0; jj < TILE_H / 2; ++jj) {      // 6 vertical pixels per thread
            const int rr = w0 + jj + 3;

            const float center = band[rr][cx];
            const float hi = center + 20.0f;
            const float lo = center - 20.0f;

            unsigned dark = 0u, bright = 0u;
            unsigned long long sc0, sc1;
#pragma unroll
            for (int k = 0; k < 16; ++k) {
                const float t = band[rr + DY[k]][cx + DX[k]];
                STEP_GE(dark,   sc0, t, hi);
                STEP_LE(bright, sc1, t, lo);
            }
            obase[(size_t)jj * IMG_W] = (det9(dark) | det9(bright)) ? 1.0f : 0.0f;
        }
        __syncthreads();   // WAR: band re-staged next rep; also pins stores per rep
    }
}

extern "C" void kernel_launch(void* const* d_in, const int* in_sizes, int n_in,
                              void* d_out, int out_size, void* d_ws, size_t ws_size,
                              hipStream_t stream) {
    const float* img = (const float*)d_in[0];
    float* out = (float*)d_out;
    const int n_img = in_sizes[0] / (IMG_H * IMG_W);   // = 4
    dim3 grid(GXB * GYB * n_img, 1, 1);                // 5400 blocks
    dim3 block(TILE_W, 2, 1);                          // 256 threads
    fast_score_kernel<<<grid, block, 0, stream>>>(img, out);
}

// Round 7
// 97.650 us; speedup vs baseline: 2.4754x; 2.4754x over previous
//
#include <hip/hip_runtime.h>

#define IMG_H 1080
#define IMG_W 1920
#define TILE_W 128
#define TILE_H 6
#define GXB (IMG_W / TILE_W)    // 15
#define GYB (IMG_H / TILE_H)    // 180
#define BAND_W 136              // cols gx0-4 .. gx0+131
#define PITCH 12                // 12 rows (y0-3..y0+8); 48B col pitch: 16B-aligned, bank-balanced

// Nonzero iff the 16-bit circular mask has 9 consecutive set bits.
// (Validated absmax=0 in prior rounds; unchanged.)
__device__ __forceinline__ unsigned det9(unsigned m) {
    unsigned x = m | (m << 16);
    unsigned t = x & (x >> 1);   // run 2
    t &= t >> 2;                 // run 4
    t &= t >> 4;                 // run 8
    t &= x >> 8;                 // run 9
    return t;
}

// m = (m << 1) | (val CMP thr) in exactly 2 VALU (v_cmp + v_addc m+m+carry).
#define STEP_GE(m, sc, val, thr)                                          \
    asm("v_cmp_ge_f32 %1, %2, %3\n\tv_addc_co_u32 %0, %1, %0, %0, %1"     \
        : "+v"(m), "=s"(sc) : "v"(val), "v"(thr))
#define STEP_LE(m, sc, val, thr)                                          \
    asm("v_cmp_le_f32 %1, %2, %3\n\tv_addc_co_u32 %0, %1, %0, %0, %1"     \
        : "+v"(m), "=s"(sc) : "v"(val), "v"(thr))

// Load one transposed column (12 rows) as 3x ds_read_b128 into cv[12].
#define LOADCOL(CV, DXCOL)                                                \
    {   const float4 q0 = *(const float4*)&bandT[cxb + (DXCOL)][0];       \
        const float4 q1 = *(const float4*)&bandT[cxb + (DXCOL)][4];       \
        const float4 q2 = *(const float4*)&bandT[cxb + (DXCOL)][8];       \
        CV[0] = q0.x; CV[1] = q0.y; CV[2]  = q0.z; CV[3]  = q0.w;         \
        CV[4] = q1.x; CV[5] = q1.y; CV[6]  = q1.z; CV[7]  = q1.w;         \
        CV[8] = q2.x; CV[9] = q2.y; CV[10] = q2.z; CV[11] = q2.w; }

// Push one arc-A tap (row offset RO = 3+DY) into all 6 pixels' dark/bright chains.
#define ATAP(CV, RO)                                                      \
    { STEP_GE(Ad[0], sc0, CV[0 + (RO)], hi[0]); STEP_LE(Ab[0], sc1, CV[0 + (RO)], lo[0]); \
      STEP_GE(Ad[1], sc0, CV[1 + (RO)], hi[1]); STEP_LE(Ab[1], sc1, CV[1 + (RO)], lo[1]); \
      STEP_GE(Ad[2], sc0, CV[2 + (RO)], hi[2]); STEP_LE(Ab[2], sc1, CV[2 + (RO)], lo[2]); \
      STEP_GE(Ad[3], sc0, CV[3 + (RO)], hi[3]); STEP_LE(Ab[3], sc1, CV[3 + (RO)], lo[3]); \
      STEP_GE(Ad[4], sc0, CV[4 + (RO)], hi[4]); STEP_LE(Ab[4], sc1, CV[4 + (RO)], lo[4]); \
      STEP_GE(Ad[5], sc0, CV[5 + (RO)], hi[5]); STEP_LE(Ab[5], sc1, CV[5 + (RO)], lo[5]); }

#define BTAP(CV, RO)                                                      \
    { STEP_GE(Bd[0], sc0, CV[0 + (RO)], hi[0]); STEP_LE(Bb[0], sc1, CV[0 + (RO)], lo[0]); \
      STEP_GE(Bd[1], sc0, CV[1 + (RO)], hi[1]); STEP_LE(Bb[1], sc1, CV[1 + (RO)], lo[1]); \
      STEP_GE(Bd[2], sc0, CV[2 + (RO)], hi[2]); STEP_LE(Bb[2], sc1, CV[2 + (RO)], lo[2]); \
      STEP_GE(Bd[3], sc0, CV[3 + (RO)], hi[3]); STEP_LE(Bb[3], sc1, CV[3 + (RO)], lo[3]); \
      STEP_GE(Bd[4], sc0, CV[4 + (RO)], hi[4]); STEP_LE(Bb[4], sc1, CV[4 + (RO)], lo[4]); \
      STEP_GE(Bd[5], sc0, CV[5 + (RO)], hi[5]); STEP_LE(Bb[5], sc1, CV[5 + (RO)], lo[5]); }

__global__ __launch_bounds__(128) void fast_score_kernel(const float* __restrict__ img,
                                                         float* __restrict__ out) {
    __shared__ float bandT[BAND_W][PITCH];   // 6528 B, column-major

    // Bijective XCD swizzle (m204 form; 10800 % 8 == 0).
    int bid = blockIdx.x;
    {
        const int nwg = gridDim.x;
        const int q = nwg >> 3, r = nwg & 7;
        const int xcd = bid & 7, idx = bid >> 3;
        bid = (xcd < r ? xcd * (q + 1) : r * (q + 1) + (xcd - r) * q) + idx;
    }
    const int bx = bid % GXB;
    const int t0 = bid / GXB;
    const int by = t0 % GYB;
    const int n  = t0 / GYB;

    const int tx  = threadIdx.x;     // 0..127
    const int gx0 = bx * TILE_W;
    const int y0  = by * TILE_H;

    const float* base = img + (size_t)n * (IMG_H * IMG_W);

    // ---- stage: transpose-in-registers, 12 coalesced row loads -> 3 ds_write_b128 ----
    for (int c = tx; c < BAND_W; c += TILE_W) {
        const int cg = min(max(gx0 - 4 + c, 0), IMG_W - 1);   // replicate clamp x
        float v[12];
#pragma unroll
        for (int r = 0; r < 12; ++r) {
            const int ry = min(max(y0 - 3 + r, 0), IMG_H - 1);  // replicate clamp y
            v[r] = base[(size_t)ry * IMG_W + cg];
        }
        *(float4*)&bandT[c][0] = make_float4(v[0], v[1], v[2],  v[3]);
        *(float4*)&bandT[c][4] = make_float4(v[4], v[5], v[6],  v[7]);
        *(float4*)&bandT[c][8] = make_float4(v[8], v[9], v[10], v[11]);
    }
    __syncthreads();

    const int cxb = tx + 4;          // band column of this thread's pixel column

    // Centers: rows 3..8 of the dx=0 column.
    float cv[12];
    LOADCOL(cv, 0);
    float hi[6], lo[6];
#pragma unroll
    for (int j = 0; j < 6; ++j) {
        hi[j] = cv[j + 3] + 20.0f;
        lo[j] = cv[j + 3] - 20.0f;
    }

    // Arc chains: A = taps k0..k7 (dx ascending), B = taps k15..k8 (dx ascending).
    unsigned Ad[6] = {0, 0, 0, 0, 0, 0}, Ab[6] = {0, 0, 0, 0, 0, 0};
    unsigned Bd[6] = {0, 0, 0, 0, 0, 0}, Bb[6] = {0, 0, 0, 0, 0, 0};
    unsigned long long sc0, sc1;

    LOADCOL(cv, -3);                 // dx=-3: A k0(DY0), k1(DY1); B k15(DY-1)
    ATAP(cv, 3); ATAP(cv, 4); BTAP(cv, 2);
    LOADCOL(cv, -2);                 // dx=-2: A k2(DY2); B k14(DY-2)
    ATAP(cv, 5); BTAP(cv, 1);
    LOADCOL(cv, -1);                 // dx=-1: A k3(DY3); B k13(DY-3)
    ATAP(cv, 6); BTAP(cv, 0);
    LOADCOL(cv, 0);                  // dx= 0: A k4(DY3); B k12(DY-3)  (CSEs with center load)
    ATAP(cv, 6); BTAP(cv, 0);
    LOADCOL(cv, 1);                  // dx=+1: A k5(DY3); B k11(DY-3)
    ATAP(cv, 6); BTAP(cv, 0);
    LOADCOL(cv, 2);                  // dx=+2: A k6(DY2); B k10(DY-2)
    ATAP(cv, 5); BTAP(cv, 1);
    LOADCOL(cv, 3);                  // dx=+3: A k7(DY1); B k9(DY-1), k8(DY0)
    ATAP(cv, 4); BTAP(cv, 2); BTAP(cv, 3);

    // Recombine: mask bit (15-k) = tap k  — bit-identical to prior validated kernels.
    float* obase = out + ((size_t)n * IMG_H + y0) * IMG_W + gx0 + tx;
#pragma unroll
    for (int j = 0; j < 6; ++j) {
        const unsigned dark   = (Ad[j] << 8) | (__brev(Bd[j]) >> 24);
        const unsigned bright = (Ab[j] << 8) | (__brev(Bb[j]) >> 24);
        obase[(size_t)j * IMG_W] = (det9(dark) | det9(bright)) ? 1.0f : 0.0f;
    }
}

extern "C" void kernel_launch(void* const* d_in, const int* in_sizes, int n_in,
                              void* d_out, int out_size, void* d_ws, size_t ws_size,
                              hipStream_t stream) {
    const float* img = (const float*)d_in[0];
    float* out = (float*)d_out;
    const int n_img = in_sizes[0] / (IMG_H * IMG_W);   // = 4
    dim3 grid(GXB * GYB * n_img, 1, 1);                // 15*180*4 = 10800 blocks
    dim3 block(TILE_W, 1, 1);                          // 128 threads (2 waves)
    fast_score_kernel<<<grid, block, 0, stream>>>(img, out);
}